// Round 1
// baseline (326.559 us; speedup 1.0000x reference)
//
#include <hip/hip_runtime.h>
#include <cstdint>
#include <cstddef>

// Problem constants (from reference)
constexpr int BB   = 2;
constexpr int NN   = 8192;
constexpr int MM   = 8192;
constexpr int CIN  = 32;
constexpr int COUT = 32;
constexpr int EE   = 16;
constexpr int KK   = 32;
// GAMMA = E*E = 256

#define WAVES_PER_BLOCK 4

// Kernel 0: transpose coeff [CIN][COUT][E] -> coeffT [E][COUT][CIN] in workspace
__global__ __launch_bounds__(256) void transpose_coeff(const float* __restrict__ coeff,
                                                       float* __restrict__ coeffT) {
    int tid = blockIdx.x * 256 + threadIdx.x;          // 0 .. 16383
    if (tid >= EE * COUT * CIN) return;
    int i = tid & 31;
    int o = (tid >> 5) & 31;
    int e = tid >> 10;
    // coeffT[(e*COUT + o)*CIN + i] = coeff[(i*COUT + o)*E + e]
    coeffT[tid] = coeff[(i * COUT + o) * EE + e];
}

// Main kernel: one wave (64 lanes) per output query point.
__global__ __launch_bounds__(256) void conv_knn_kernel(
    const float* __restrict__ points_in,   // [B][N][2]
    const float* __restrict__ values_in,   // [B][N][CIN]
    const float* __restrict__ points_out,  // [B][M][2]
    const float* __restrict__ coeffT,      // [E][COUT][CIN]
    const float* __restrict__ bias,        // [COUT]
    float* __restrict__ out_uiv,           // [B*M][K][2]
    float* __restrict__ out_idx,           // [B*M][K]  (indices as floats)
    float* __restrict__ out_val)           // [B*M][COUT]
{
    __shared__ float TL[WAVES_PER_BLOCK][EE][36];   // padded T[e][i]

    const int lane  = threadIdx.x & 63;
    const int wslot = threadIdx.x >> 6;
    const int wid   = blockIdx.x * WAVES_PER_BLOCK + wslot;   // 0 .. B*M-1
    const int b     = wid >> 13;           // / M
    const int m     = wid & (MM - 1);

    const float2* P = ((const float2*)points_in) + (size_t)b * NN;
    const float2  q = ((const float2*)points_out)[(size_t)b * MM + m];

    const float INF = __builtin_inff();

    // --- wave-collective exact top-K (sorted ascending by (dist, idx), lanes 0..31) ---
    float bd = INF;            // best distances (one per lane)
    int   bi = 0x7FFFFFFF;     // best indices
    float t  = INF;            // current threshold = entry 31 (kth best)
    int   ti = 0x7FFFFFFF;

    for (int r = 0; r < NN / 64; ++r) {
        const int ci = (r << 6) | lane;
        const float2 p = P[ci];
        // Exact fp32 (no FMA contraction), correctly-rounded sqrt: matches numpy.
        const float dx = q.x - p.x;
        const float dy = q.y - p.y;
        const float d2 = __fadd_rn(__fmul_rn(dx, dx), __fmul_rn(dy, dy));
        const float d  = __fsqrt_rn(d2);

        const bool pred = (d < t) || (d == t && ci < ti);
        unsigned long long cm = __ballot(pred);
        while (cm) {
            const int l = __ffsll((unsigned long long)cm) - 1;
            cm &= cm - 1;
            const float v  = __shfl(d, l);
            const int   vi = __shfl(ci, l);
            // sorted position = #entries with key < (v, vi)
            const bool cl = (bd < v) || (bd == v && bi < vi);
            const int pos = (int)__popcll(__ballot(cl));
            const float sd = __shfl_up(bd, 1);
            const int   si = __shfl_up(bi, 1);
            float nbd = (lane < pos) ? bd : ((lane == pos) ? v  : sd);
            int   nbi = (lane < pos) ? bi : ((lane == pos) ? vi : si);
            bd = (lane >= 32) ? INF        : nbd;
            bi = (lane >= 32) ? 0x7FFFFFFF : nbi;
            t  = __shfl(bd, 31);
            ti = __shfl(bi, 31);
        }
    }

    // --- outputs 0 and 1: uiv_k and idx (as float) ---
    if (lane < KK) {
        const float2 pk = P[bi];
        float2 u;
        u.x = q.x - pk.x;
        u.y = q.y - pk.y;
        ((float2*)out_uiv)[(size_t)wid * KK + lane] = u;
        out_idx[(size_t)wid * KK + lane] = (float)bi;
    }

    // --- T[e][i] = sum_k exp(-256*(r_k - mu_e)^2) * values_in[b, idx_k, i] ---
    {
        const int e  = lane >> 2;          // 0..15
        const int ib = (lane & 3) << 3;    // 0,8,16,24
        const float mu = (float)e * (1.0f / 15.0f);
        float acc0 = 0.f, acc1 = 0.f, acc2 = 0.f, acc3 = 0.f;
        float acc4 = 0.f, acc5 = 0.f, acc6 = 0.f, acc7 = 0.f;
        for (int k = 0; k < KK; ++k) {
            const float rk  = __shfl(bd, k);
            const int   bik = __shfl(bi, k);
            const float dl  = rk - mu;
            const float w   = __expf(-256.0f * dl * dl);
            const float4* vr = (const float4*)(values_in + ((size_t)b * NN + bik) * CIN + ib);
            const float4 v0 = vr[0];
            const float4 v1 = vr[1];
            acc0 += w * v0.x; acc1 += w * v0.y; acc2 += w * v0.z; acc3 += w * v0.w;
            acc4 += w * v1.x; acc5 += w * v1.y; acc6 += w * v1.z; acc7 += w * v1.w;
        }
        float* tw = &TL[wslot][e][ib];
        tw[0] = acc0; tw[1] = acc1; tw[2] = acc2; tw[3] = acc3;
        tw[4] = acc4; tw[5] = acc5; tw[6] = acc6; tw[7] = acc7;
    }

    __syncthreads();

    // --- out[o] = (1/K) * sum_{e,i} coeffT[e][o][i] * T[e][i] + bias[o] ---
    {
        const int o = lane & 31;
        const int h = lane >> 5;           // e half: 0 -> e 0..7, 1 -> e 8..15
        float s = 0.f;
        const float* TW = &TL[wslot][0][0];
        for (int e = h * 8; e < h * 8 + 8; ++e) {
            const float4* crow = (const float4*)(coeffT + ((size_t)e * COUT + o) * CIN);
            const float4* trow = (const float4*)(TW + e * 36);
#pragma unroll
            for (int i4 = 0; i4 < 8; ++i4) {
                const float4 c  = crow[i4];
                const float4 tv = trow[i4];
                s += c.x * tv.x + c.y * tv.y + c.z * tv.z + c.w * tv.w;
            }
        }
        s += __shfl_xor(s, 32);
        if (lane < 32) {
            out_val[(size_t)wid * COUT + o] = s * (1.0f / 32.0f) + bias[o];
        }
    }
}

extern "C" void kernel_launch(void* const* d_in, const int* in_sizes, int n_in,
                              void* d_out, int out_size, void* d_ws, size_t ws_size,
                              hipStream_t stream) {
    const float* points_in  = (const float*)d_in[0];
    const float* values_in  = (const float*)d_in[1];
    const float* points_out = (const float*)d_in[2];
    const float* coeff      = (const float*)d_in[3];
    const float* bias       = (const float*)d_in[4];

    float* out     = (float*)d_out;
    float* out_uiv = out;                                        // B*M*K*2
    float* out_idx = out + (size_t)BB * MM * KK * 2;             // B*M*K
    float* out_val = out_idx + (size_t)BB * MM * KK;             // B*M*COUT

    float* coeffT = (float*)d_ws;                                // E*COUT*CIN floats = 64 KB

    hipLaunchKernelGGL(transpose_coeff, dim3(64), dim3(256), 0, stream, coeff, coeffT);

    const int total_waves = BB * MM;                             // 16384
    const int blocks = total_waves / WAVES_PER_BLOCK;            // 4096
    hipLaunchKernelGGL(conv_knn_kernel, dim3(blocks), dim3(256), 0, stream,
                       points_in, values_in, points_out, coeffT, bias,
                       out_uiv, out_idx, out_val);
}

// Round 2
// 233.386 us; speedup vs baseline: 1.3992x; 1.3992x over previous
//
#include <hip/hip_runtime.h>
#include <cstdint>
#include <cstddef>

// Problem constants (from reference)
constexpr int BB   = 2;
constexpr int NN   = 8192;
constexpr int MM   = 8192;
constexpr int CIN  = 32;
constexpr int COUT = 32;
constexpr int EE   = 16;
constexpr int KK   = 32;
// GAMMA = E*E = 256

#define WAVES_PER_BLOCK 4

// Kernel 0: transpose coeff [CIN][COUT][E] -> coeffT [E][COUT][CIN] in workspace
__global__ __launch_bounds__(256) void transpose_coeff(const float* __restrict__ coeff,
                                                       float* __restrict__ coeffT) {
    int tid = blockIdx.x * 256 + threadIdx.x;          // 0 .. 16383
    if (tid >= EE * COUT * CIN) return;
    int i = tid & 31;
    int o = (tid >> 5) & 31;
    int e = tid >> 10;
    coeffT[tid] = coeff[(i * COUT + o) * EE + e];
}

// Main kernel: one wave (64 lanes) per output query point.
__global__ __launch_bounds__(256) void conv_knn_kernel(
    const float* __restrict__ points_in,   // [B][N][2]
    const float* __restrict__ values_in,   // [B][N][CIN]
    const float* __restrict__ points_out,  // [B][M][2]
    const float* __restrict__ coeffT,      // [E][COUT][CIN]
    const float* __restrict__ bias,        // [COUT]
    float* __restrict__ out_uiv,           // [B*M][K][2]
    float* __restrict__ out_idx,           // [B*M][K]  (indices as floats)
    float* __restrict__ out_val)           // [B*M][COUT]
{
    __shared__ float TL[WAVES_PER_BLOCK][EE][36];   // padded T[e][i]

    const int lane  = threadIdx.x & 63;
    const int wslot = threadIdx.x >> 6;
    const int wid   = blockIdx.x * WAVES_PER_BLOCK + wslot;   // 0 .. B*M-1
    const int b     = wid >> 13;           // / M
    const int m     = wid & (MM - 1);

    const float2* P  = ((const float2*)points_in) + (size_t)b * NN;
    const float4* P4 = (const float4*)P;                      // 2 points per float4
    const float2  q  = ((const float2*)points_out)[(size_t)b * MM + m];

    const float INF = __builtin_inff();

    // ---------------- Pass A: per-lane min of d^2 (filter key, FMA form) -------------
    float m0 = INF;
    for (int r = 0; r < 64; ++r) {
        const float4 pp = P4[(r << 6) | lane];
        const float dx0 = q.x - pp.x, dy0 = q.y - pp.y;
        const float dx1 = q.x - pp.z, dy1 = q.y - pp.w;
        const float d20 = __builtin_fmaf(dy0, dy0, __fmul_rn(dx0, dx0));
        const float d21 = __builtin_fmaf(dy1, dy1, __fmul_rn(dx1, dx1));
        m0 = fminf(m0, fminf(d20, d21));
    }

    // ---------------- tau^2 = 32nd smallest of the 64 lane minima (bitonic sort) -----
    // Upper bound proof: <=31 values in the full set are strictly < d2_(32), so <=31
    // lane minima are strictly < d2_(32)  =>  32nd smallest lane-min >= d2_(32).
    {
        float v = m0;
#pragma unroll
        for (int k = 2; k <= 64; k <<= 1) {
#pragma unroll
            for (int j = k >> 1; j > 0; j >>= 1) {
                const float o  = __shfl_xor(v, j);
                const bool up    = ((lane & k) == 0);
                const bool lower = ((lane & j) == 0);
                const float mn = fminf(v, o), mx = fmaxf(v, o);
                v = (lower == up) ? mn : mx;
            }
        }
        m0 = __shfl(v, 31);                 // reuse m0 as tau2
    }
    const float tau2b = m0 * (1.0f + 4e-6f);   // slack: sqrt-tie + fma-vs-add rounding

    // ---------------- Pass B: filter by d2 <= tau2b, insert survivors exactly --------
    // List is length 64 (lanes 0..63), sorted ascending by (d, idx) lex; final answer
    // is lanes 0..31. Exact d uses numpy semantics: no FMA, correctly rounded sqrt.
    float bd = INF;            // sorted distances
    int   bi = 0x7FFFFFFF;     // sorted indices

    for (int r = 0; r < 64; ++r) {
        const float4 pp = P4[(r << 6) | lane];
        const int ci0 = ((r << 6) | lane) << 1;
        const int ci1 = ci0 + 1;
        const float dx0 = q.x - pp.x, dy0 = q.y - pp.y;
        const float dx1 = q.x - pp.z, dy1 = q.y - pp.w;
        const float d20 = __builtin_fmaf(dy0, dy0, __fmul_rn(dx0, dx0));
        const float d21 = __builtin_fmaf(dy1, dy1, __fmul_rn(dx1, dx1));
        unsigned long long cm0 = __ballot(d20 <= tau2b);
        unsigned long long cm1 = __ballot(d21 <= tau2b);
        if (cm0 | cm1) {
            // exact distances (match numpy: rn mul/add, rn sqrt)
            const float e0 = __fsqrt_rn(__fadd_rn(__fmul_rn(dx0, dx0), __fmul_rn(dy0, dy0)));
            const float e1 = __fsqrt_rn(__fadd_rn(__fmul_rn(dx1, dx1), __fmul_rn(dy1, dy1)));
            while (cm0) {
                const int l = __builtin_ctzll(cm0); cm0 &= cm0 - 1;
                const float v  = __shfl(e0, l);
                const int   vi = __shfl(ci0, l);
                const bool cl = (bd < v) || (bd == v && bi < vi);
                const int pos = (int)__popcll(__ballot(cl));
                const float sd = __shfl_up(bd, 1);
                const int   si = __shfl_up(bi, 1);
                bd = (lane < pos) ? bd : ((lane == pos) ? v  : sd);
                bi = (lane < pos) ? bi : ((lane == pos) ? vi : si);
            }
            while (cm1) {
                const int l = __builtin_ctzll(cm1); cm1 &= cm1 - 1;
                const float v  = __shfl(e1, l);
                const int   vi = __shfl(ci1, l);
                const bool cl = (bd < v) || (bd == v && bi < vi);
                const int pos = (int)__popcll(__ballot(cl));
                const float sd = __shfl_up(bd, 1);
                const int   si = __shfl_up(bi, 1);
                bd = (lane < pos) ? bd : ((lane == pos) ? v  : sd);
                bi = (lane < pos) ? bi : ((lane == pos) ? vi : si);
            }
        }
    }

    // ---------------- outputs 0 and 1: uiv_k and idx (as float) ----------------------
    if (lane < KK) {
        const float2 pk = P[bi];
        float2 u;
        u.x = q.x - pk.x;
        u.y = q.y - pk.y;
        ((float2*)out_uiv)[(size_t)wid * KK + lane] = u;
        out_idx[(size_t)wid * KK + lane] = (float)bi;
    }

    // ---- T[e][i] = sum_k exp(-256*(r_k - mu_e)^2) * values_in[b, idx_k, i] ----------
    {
        const int e  = lane >> 2;          // 0..15
        const int ib = (lane & 3) << 3;    // 0,8,16,24
        const float mu = (float)e * (1.0f / 15.0f);
        float acc0 = 0.f, acc1 = 0.f, acc2 = 0.f, acc3 = 0.f;
        float acc4 = 0.f, acc5 = 0.f, acc6 = 0.f, acc7 = 0.f;
#pragma unroll
        for (int k = 0; k < KK; ++k) {
            const float rk  = __shfl(bd, k);
            const int   bik = __shfl(bi, k);
            const float dl  = rk - mu;
            const float w   = __expf(-256.0f * dl * dl);
            const float4* vr = (const float4*)(values_in + ((size_t)b * NN + bik) * CIN + ib);
            const float4 v0 = vr[0];
            const float4 v1 = vr[1];
            acc0 += w * v0.x; acc1 += w * v0.y; acc2 += w * v0.z; acc3 += w * v0.w;
            acc4 += w * v1.x; acc5 += w * v1.y; acc6 += w * v1.z; acc7 += w * v1.w;
        }
        float* tw = &TL[wslot][e][ib];
        tw[0] = acc0; tw[1] = acc1; tw[2] = acc2; tw[3] = acc3;
        tw[4] = acc4; tw[5] = acc5; tw[6] = acc6; tw[7] = acc7;
    }

    __syncthreads();

    // ---- out[o] = (1/K) * sum_{e,i} coeffT[e][o][i] * T[e][i] + bias[o] -------------
    {
        const int o = lane & 31;
        const int h = lane >> 5;           // e half: 0 -> e 0..7, 1 -> e 8..15
        float s = 0.f;
        const float* TW = &TL[wslot][0][0];
        for (int e = h * 8; e < h * 8 + 8; ++e) {
            const float4* crow = (const float4*)(coeffT + ((size_t)e * COUT + o) * CIN);
            const float4* trow = (const float4*)(TW + e * 36);
#pragma unroll
            for (int i4 = 0; i4 < 8; ++i4) {
                const float4 c  = crow[i4];
                const float4 tv = trow[i4];
                s += c.x * tv.x + c.y * tv.y + c.z * tv.z + c.w * tv.w;
            }
        }
        s += __shfl_xor(s, 32);
        if (lane < 32) {
            out_val[(size_t)wid * COUT + o] = s * (1.0f / 32.0f) + bias[o];
        }
    }
}

extern "C" void kernel_launch(void* const* d_in, const int* in_sizes, int n_in,
                              void* d_out, int out_size, void* d_ws, size_t ws_size,
                              hipStream_t stream) {
    const float* points_in  = (const float*)d_in[0];
    const float* values_in  = (const float*)d_in[1];
    const float* points_out = (const float*)d_in[2];
    const float* coeff      = (const float*)d_in[3];
    const float* bias       = (const float*)d_in[4];

    float* out     = (float*)d_out;
    float* out_uiv = out;                                        // B*M*K*2
    float* out_idx = out + (size_t)BB * MM * KK * 2;             // B*M*K
    float* out_val = out_idx + (size_t)BB * MM * KK;             // B*M*COUT

    float* coeffT = (float*)d_ws;                                // E*COUT*CIN floats = 64 KB

    hipLaunchKernelGGL(transpose_coeff, dim3(64), dim3(256), 0, stream, coeff, coeffT);

    const int total_waves = BB * MM;                             // 16384
    const int blocks = total_waves / WAVES_PER_BLOCK;            // 4096
    hipLaunchKernelGGL(conv_knn_kernel, dim3(blocks), dim3(256), 0, stream,
                       points_in, values_in, points_out, coeffT, bias,
                       out_uiv, out_idx, out_val);
}

// Round 3
// 232.605 us; speedup vs baseline: 1.4039x; 1.0034x over previous
//
#include <hip/hip_runtime.h>
#include <cstdint>
#include <cstddef>

// Problem constants (from reference)
constexpr int BB   = 2;
constexpr int NN   = 8192;
constexpr int MM   = 8192;
constexpr int CIN  = 32;
constexpr int COUT = 32;
constexpr int EE   = 16;
constexpr int KK   = 32;
// GAMMA = E*E = 256

#define WAVES_PER_BLOCK 4
#define CAP 128

// Kernel 0: transpose coeff [CIN][COUT][E] -> coeffT [E][COUT][CIN] in workspace
__global__ __launch_bounds__(256) void transpose_coeff(const float* __restrict__ coeff,
                                                       float* __restrict__ coeffT) {
    int tid = blockIdx.x * 256 + threadIdx.x;          // 0 .. 16383
    if (tid >= EE * COUT * CIN) return;
    int i = tid & 31;
    int o = (tid >> 5) & 31;
    int e = tid >> 10;
    coeffT[tid] = coeff[(i * COUT + o) * EE + e];
}

// Main kernel: one wave (64 lanes) per output query point.
__global__ __launch_bounds__(256) void conv_knn_kernel(
    const float* __restrict__ points_in,   // [B][N][2]
    const float* __restrict__ values_in,   // [B][N][CIN]
    const float* __restrict__ points_out,  // [B][M][2]
    const float* __restrict__ coeffT,      // [E][COUT][CIN]
    const float* __restrict__ bias,        // [COUT]
    float* __restrict__ out_uiv,           // [B*M][K][2]
    float* __restrict__ out_idx,           // [B*M][K]  (indices as floats)
    float* __restrict__ out_val)           // [B*M][COUT]
{
    __shared__ float TL[WAVES_PER_BLOCK][EE][36];            // padded T[e][i]
    __shared__ unsigned long long KEY[WAVES_PER_BLOCK][CAP]; // survivor keys

    const int lane  = threadIdx.x & 63;
    const int wslot = threadIdx.x >> 6;
    const int wid   = blockIdx.x * WAVES_PER_BLOCK + wslot;   // 0 .. B*M-1
    const int b     = wid >> 13;           // / M
    const int m     = wid & (MM - 1);

    const float2* P  = ((const float2*)points_in) + (size_t)b * NN;
    const float4* P4 = (const float4*)P;                      // 2 points per float4
    const float2  q  = ((const float2*)points_out)[(size_t)b * MM + m];

    const float INF = __builtin_inff();

    // ---------------- Pass A: per-lane min of d^2 (filter key, FMA form) -------------
    float m0 = INF;
    for (int r = 0; r < 64; ++r) {
        const float4 pp = P4[(r << 6) | lane];
        const float dx0 = q.x - pp.x, dy0 = q.y - pp.y;
        const float dx1 = q.x - pp.z, dy1 = q.y - pp.w;
        const float d20 = __builtin_fmaf(dy0, dy0, __fmul_rn(dx0, dx0));
        const float d21 = __builtin_fmaf(dy1, dy1, __fmul_rn(dx1, dx1));
        m0 = fminf(m0, fminf(d20, d21));
    }

    // ---------------- tau^2 = 32nd smallest of the 64 lane minima (bitonic sort) -----
    // Upper bound proof: <=31 values in the full set are strictly < d2_(32), so <=31
    // lane minima are strictly < d2_(32)  =>  32nd smallest lane-min >= d2_(32).
    {
        float v = m0;
#pragma unroll
        for (int k = 2; k <= 64; k <<= 1) {
#pragma unroll
            for (int j = k >> 1; j > 0; j >>= 1) {
                const float o  = __shfl_xor(v, j);
                const bool up    = ((lane & k) == 0);
                const bool lower = ((lane & j) == 0);
                const float mn = fminf(v, o), mx = fmaxf(v, o);
                v = (lower == up) ? mn : mx;
            }
        }
        m0 = __shfl(v, 31);                 // reuse m0 as tau2
    }
    const float tau2b = m0 * (1.0f + 4e-6f);   // slack: sqrt-tie + fma-vs-add rounding

    // ---------------- Pass B: filter + COMPACT survivors into LDS (no serial chain) --
    // Key = (float_bits(exact d) << 32) | idx : u64 ascending == lex (d, idx) ascending
    // == numpy top_k stable order. Exact d: rn mul/add (no FMA), rn sqrt.
    const unsigned long long lmlt = (1ull << lane) - 1ull;   // lanes below me
    int base = 0;                                            // wave-uniform count

    for (int r = 0; r < 64; ++r) {
        const float4 pp = P4[(r << 6) | lane];
        const int ci0 = ((r << 6) | lane) << 1;
        const int ci1 = ci0 + 1;
        const float dx0 = q.x - pp.x, dy0 = q.y - pp.y;
        const float dx1 = q.x - pp.z, dy1 = q.y - pp.w;
        const float d20 = __builtin_fmaf(dy0, dy0, __fmul_rn(dx0, dx0));
        const float d21 = __builtin_fmaf(dy1, dy1, __fmul_rn(dx1, dx1));
        const bool p0 = (d20 <= tau2b);
        const bool p1 = (d21 <= tau2b);
        const unsigned long long bm0 = __ballot(p0);
        const unsigned long long bm1 = __ballot(p1);
        if (bm0 | bm1) {
            const float e0 = __fsqrt_rn(__fadd_rn(__fmul_rn(dx0, dx0), __fmul_rn(dy0, dy0)));
            const float e1 = __fsqrt_rn(__fadd_rn(__fmul_rn(dx1, dx1), __fmul_rn(dy1, dy1)));
            const int c0 = __popcll(bm0);
            const int pos0 = base + __popcll(bm0 & lmlt);
            const int pos1 = base + c0 + __popcll(bm1 & lmlt);
            if (p0 && pos0 < CAP)
                KEY[wslot][pos0] = ((unsigned long long)__float_as_uint(e0) << 32) | (unsigned)ci0;
            if (p1 && pos1 < CAP)
                KEY[wslot][pos1] = ((unsigned long long)__float_as_uint(e1) << 32) | (unsigned)ci1;
            base += c0 + __popcll(bm1);
        }
    }

    float bd;   // final: distance of neighbor #lane (lanes 0..31 valid)
    int   bi;   // final: index of neighbor #lane

    if (base <= CAP) {
        // pad to CAP with +inf keys
        if (lane      >= base) KEY[wslot][lane]      = ~0ull;
        if (lane + 64 >= base) KEY[wslot][lane + 64] = ~0ull;
        unsigned long long k0 = KEY[wslot][lane];
        unsigned long long k1 = KEY[wslot][lane + 64];

        // ---------------- bitonic sort of 128 u64 keys, ascending --------------------
        // virtual position v = reg*64 + lane; j==64 step is the in-register compare.
#pragma unroll
        for (int k = 2; k <= 128; k <<= 1) {
#pragma unroll
            for (int j = k >> 1; j > 0; j >>= 1) {
                if (j == 64) {
                    // only k==128: ascending merge across regs (same lane)
                    const unsigned long long lo = (k0 < k1) ? k0 : k1;
                    const unsigned long long hi = (k0 < k1) ? k1 : k0;
                    k0 = lo; k1 = hi;
                } else {
                    const unsigned long long o0 = __shfl_xor(k0, j);
                    const unsigned long long o1 = __shfl_xor(k1, j);
                    const bool lower = ((lane & j) == 0);
                    const bool up0 = ((lane & k) == 0);          // v = lane
                    const bool up1 = (((lane + 64) & k) == 0);   // v = lane + 64
                    const bool keepmin0 = (lower == up0);
                    const bool keepmin1 = (lower == up1);
                    k0 = (keepmin0 == (k0 < o0)) ? k0 : o0;
                    k1 = (keepmin1 == (k1 < o1)) ? k1 : o1;
                }
            }
        }
        bd = __uint_as_float((unsigned)(k0 >> 32));
        bi = (int)(unsigned)(k0 & 0xffffffffull);
    } else {
        // ------- overflow fallback (astronomically rare, deterministic-correct) ------
        float fd = INF;
        int   fi = 0x7FFFFFFF;
        for (int r = 0; r < 64; ++r) {
            const float4 pp = P4[(r << 6) | lane];
            const int ci0 = ((r << 6) | lane) << 1;
            const int ci1 = ci0 + 1;
            const float dx0 = q.x - pp.x, dy0 = q.y - pp.y;
            const float dx1 = q.x - pp.z, dy1 = q.y - pp.w;
            const float d20 = __builtin_fmaf(dy0, dy0, __fmul_rn(dx0, dx0));
            const float d21 = __builtin_fmaf(dy1, dy1, __fmul_rn(dx1, dx1));
            unsigned long long cm0 = __ballot(d20 <= tau2b);
            unsigned long long cm1 = __ballot(d21 <= tau2b);
            if (cm0 | cm1) {
                const float e0 = __fsqrt_rn(__fadd_rn(__fmul_rn(dx0, dx0), __fmul_rn(dy0, dy0)));
                const float e1 = __fsqrt_rn(__fadd_rn(__fmul_rn(dx1, dx1), __fmul_rn(dy1, dy1)));
                while (cm0) {
                    const int l = __builtin_ctzll(cm0); cm0 &= cm0 - 1;
                    const float v  = __shfl(e0, l);
                    const int   vi = __shfl(ci0, l);
                    const bool cl = (fd < v) || (fd == v && fi < vi);
                    const int pos = (int)__popcll(__ballot(cl));
                    const float sd = __shfl_up(fd, 1);
                    const int   si = __shfl_up(fi, 1);
                    fd = (lane < pos) ? fd : ((lane == pos) ? v  : sd);
                    fi = (lane < pos) ? fi : ((lane == pos) ? vi : si);
                }
                while (cm1) {
                    const int l = __builtin_ctzll(cm1); cm1 &= cm1 - 1;
                    const float v  = __shfl(e1, l);
                    const int   vi = __shfl(ci1, l);
                    const bool cl = (fd < v) || (fd == v && fi < vi);
                    const int pos = (int)__popcll(__ballot(cl));
                    const float sd = __shfl_up(fd, 1);
                    const int   si = __shfl_up(fi, 1);
                    fd = (lane < pos) ? fd : ((lane == pos) ? v  : sd);
                    fi = (lane < pos) ? fi : ((lane == pos) ? vi : si);
                }
            }
        }
        bd = fd;
        bi = fi;
    }

    // ---------------- outputs 0 and 1: uiv_k and idx (as float) ----------------------
    if (lane < KK) {
        const float2 pk = P[bi];
        float2 u;
        u.x = q.x - pk.x;
        u.y = q.y - pk.y;
        ((float2*)out_uiv)[(size_t)wid * KK + lane] = u;
        out_idx[(size_t)wid * KK + lane] = (float)bi;
    }

    // ---- T[e][i] = sum_k exp(-256*(r_k - mu_e)^2) * values_in[b, idx_k, i] ----------
    {
        const int e  = lane >> 2;          // 0..15
        const int ib = (lane & 3) << 3;    // 0,8,16,24
        const float mu = (float)e * (1.0f / 15.0f);
        float acc0 = 0.f, acc1 = 0.f, acc2 = 0.f, acc3 = 0.f;
        float acc4 = 0.f, acc5 = 0.f, acc6 = 0.f, acc7 = 0.f;
#pragma unroll
        for (int k = 0; k < KK; ++k) {
            const float rk  = __shfl(bd, k);
            const int   bik = __shfl(bi, k);
            const float dl  = rk - mu;
            const float w   = __expf(-256.0f * dl * dl);
            const float4* vr = (const float4*)(values_in + ((size_t)b * NN + bik) * CIN + ib);
            const float4 v0 = vr[0];
            const float4 v1 = vr[1];
            acc0 += w * v0.x; acc1 += w * v0.y; acc2 += w * v0.z; acc3 += w * v0.w;
            acc4 += w * v1.x; acc5 += w * v1.y; acc6 += w * v1.z; acc7 += w * v1.w;
        }
        float* tw = &TL[wslot][e][ib];
        tw[0] = acc0; tw[1] = acc1; tw[2] = acc2; tw[3] = acc3;
        tw[4] = acc4; tw[5] = acc5; tw[6] = acc6; tw[7] = acc7;
    }

    __syncthreads();

    // ---- out[o] = (1/K) * sum_{e,i} coeffT[e][o][i] * T[e][i] + bias[o] -------------
    {
        const int o = lane & 31;
        const int h = lane >> 5;           // e half: 0 -> e 0..7, 1 -> e 8..15
        float s = 0.f;
        const float* TW = &TL[wslot][0][0];
        for (int e = h * 8; e < h * 8 + 8; ++e) {
            const float4* crow = (const float4*)(coeffT + ((size_t)e * COUT + o) * CIN);
            const float4* trow = (const float4*)(TW + e * 36);
#pragma unroll
            for (int i4 = 0; i4 < 8; ++i4) {
                const float4 c  = crow[i4];
                const float4 tv = trow[i4];
                s += c.x * tv.x + c.y * tv.y + c.z * tv.z + c.w * tv.w;
            }
        }
        s += __shfl_xor(s, 32);
        if (lane < 32) {
            out_val[(size_t)wid * COUT + o] = s * (1.0f / 32.0f) + bias[o];
        }
    }
}

extern "C" void kernel_launch(void* const* d_in, const int* in_sizes, int n_in,
                              void* d_out, int out_size, void* d_ws, size_t ws_size,
                              hipStream_t stream) {
    const float* points_in  = (const float*)d_in[0];
    const float* values_in  = (const float*)d_in[1];
    const float* points_out = (const float*)d_in[2];
    const float* coeff      = (const float*)d_in[3];
    const float* bias       = (const float*)d_in[4];

    float* out     = (float*)d_out;
    float* out_uiv = out;                                        // B*M*K*2
    float* out_idx = out + (size_t)BB * MM * KK * 2;             // B*M*K
    float* out_val = out_idx + (size_t)BB * MM * KK;             // B*M*COUT

    float* coeffT = (float*)d_ws;                                // E*COUT*CIN floats = 64 KB

    hipLaunchKernelGGL(transpose_coeff, dim3(64), dim3(256), 0, stream, coeff, coeffT);

    const int total_waves = BB * MM;                             // 16384
    const int blocks = total_waves / WAVES_PER_BLOCK;            // 4096
    hipLaunchKernelGGL(conv_knn_kernel, dim3(blocks), dim3(256), 0, stream,
                       points_in, values_in, points_out, coeffT, bias,
                       out_uiv, out_idx, out_val);
}

// Round 4
// 184.355 us; speedup vs baseline: 1.7714x; 1.2617x over previous
//
#include <hip/hip_runtime.h>
#include <cstdint>
#include <cstddef>

// Problem constants (from reference)
constexpr int BB   = 2;
constexpr int NN   = 8192;
constexpr int MM   = 8192;
constexpr int CIN  = 32;
constexpr int COUT = 32;
constexpr int EE   = 16;
constexpr int KK   = 32;
constexpr int GRID = 32;              // binning grid (h = 1/32, ~8 pts/cell)
constexpr int NCELL = GRID * GRID;

#define WPB 4
#define CAP 128

// Workspace layout (bytes)
constexpr size_t OFS_COEFFT = 0;        // 16384 f = 65536 B
constexpr size_t OFS_COUNTS = 65536;    // 2*1024 i = 8192 B
constexpr size_t OFS_CURSOR = 73728;    // 2*1024 i = 8192 B
constexpr size_t OFS_STARTS = 81920;    // 2*1025 i = 8200 B (pad to 8704)
constexpr size_t OFS_PTSS   = 90624;    // 2*8192 float2 = 131072 B
constexpr size_t OFS_IDXS   = 221696;   // 2*8192 i = 65536 B  (total 287232 B)

// ---- coeff [CIN][COUT][E] -> coeffT [E][COUT][CIN] ------------------------------
__global__ __launch_bounds__(256) void transpose_coeff(const float* __restrict__ coeff,
                                                       float* __restrict__ coeffT) {
    int tid = blockIdx.x * 256 + threadIdx.x;
    if (tid >= EE * COUT * CIN) return;
    int i = tid & 31;
    int o = (tid >> 5) & 31;
    int e = tid >> 10;
    coeffT[tid] = coeff[(i * COUT + o) * EE + e];
}

// ---- binning: zero, count, scan, scatter ----------------------------------------
__global__ __launch_bounds__(256) void bin_zero(int* __restrict__ p) {
    int t = blockIdx.x * 256 + threadIdx.x;       // 4096 ints: counts + cursor
    if (t < 2 * 2 * NCELL) p[t] = 0;
}

__device__ __forceinline__ int cell_of(float2 p) {
    int cx = min(GRID - 1, max(0, (int)(p.x * (float)GRID)));
    int cy = min(GRID - 1, max(0, (int)(p.y * (float)GRID)));
    return cy * GRID + cx;
}

__global__ __launch_bounds__(256) void bin_count(const float* __restrict__ pts,
                                                 int* __restrict__ counts) {
    int t = blockIdx.x * 256 + threadIdx.x;       // 0 .. B*N-1
    int b = t >> 13, i = t & (NN - 1);
    float2 p = ((const float2*)pts)[(size_t)b * NN + i];
    atomicAdd(&counts[b * NCELL + cell_of(p)], 1);
}

__global__ __launch_bounds__(1024) void bin_scan(const int* __restrict__ counts,
                                                 int* __restrict__ starts) {
    __shared__ int sm[NCELL];
    const int t = threadIdx.x;
    for (int b = 0; b < BB; ++b) {
        sm[t] = counts[b * NCELL + t];
        __syncthreads();
        for (int off = 1; off < NCELL; off <<= 1) {
            int v = (t >= off) ? sm[t - off] : 0;
            __syncthreads();
            sm[t] += v;
            __syncthreads();
        }
        starts[b * (NCELL + 1) + t + 1] = sm[t];
        if (t == 0) starts[b * (NCELL + 1)] = 0;
        __syncthreads();
    }
}

__global__ __launch_bounds__(256) void bin_scatter(const float* __restrict__ pts,
                                                   const int* __restrict__ starts,
                                                   int* __restrict__ cursor,
                                                   float2* __restrict__ pts_s,
                                                   int* __restrict__ idx_s) {
    int t = blockIdx.x * 256 + threadIdx.x;
    int b = t >> 13, i = t & (NN - 1);
    float2 p = ((const float2*)pts)[(size_t)b * NN + i];
    int cell = cell_of(p);
    int pos = starts[b * (NCELL + 1) + cell] + atomicAdd(&cursor[b * NCELL + cell], 1);
    pts_s[(size_t)b * NN + pos] = p;     // intra-cell order nondeterministic; final
    idx_s[(size_t)b * NN + pos] = i;     // sort by (d, orig idx) makes output exact.
}

// ---- main query kernel: one wave per output point -------------------------------
__global__ __launch_bounds__(256) void conv_query(
    const float2* __restrict__ pts_s, const int* __restrict__ idx_s,
    const int* __restrict__ starts,
    const float* __restrict__ points_in, const float* __restrict__ values_in,
    const float* __restrict__ points_out,
    const float* __restrict__ coeffT, const float* __restrict__ bias,
    float* __restrict__ out_uiv, float* __restrict__ out_idx,
    float* __restrict__ out_val)
{
    __shared__ float TL[WPB][EE][36];
    __shared__ unsigned long long KEY[WPB][CAP];

    const int lane  = threadIdx.x & 63;
    const int wslot = threadIdx.x >> 6;
    const int wid   = blockIdx.x * WPB + wslot;
    const int b     = wid >> 13;
    const int m     = wid & (MM - 1);

    const float2* PS = pts_s + (size_t)b * NN;
    const int*    IS = idx_s + (size_t)b * NN;
    const int*    ST = starts + b * (NCELL + 1);
    const float2* P  = ((const float2*)points_in) + (size_t)b * NN;
    const float2  q  = ((const float2*)points_out)[(size_t)b * MM + m];

    const float INF = __builtin_inff();
    const float h = 1.0f / (float)GRID;
    const int cx = min(GRID - 1, max(0, (int)(q.x * (float)GRID)));
    const int cy = min(GRID - 1, max(0, (int)(q.y * (float)GRID)));
    const unsigned long long lmlt = (1ull << lane) - 1ull;

    float bd;   // sorted exact distance (lane holds entry #lane)
    int   bi;   // sorted original index
    int L = 2;

    for (;;) {
        const int xlo = max(cx - L, 0), xhi = min(cx + L, GRID - 1);
        const int ylo = max(cy - L, 0), yhi = min(cy + L, GRID - 1);
        const int nrows = yhi - ylo + 1;          // <= 32 <= 64 lanes

        // prefetch per-row contiguous segment bounds (cells in a row are adjacent)
        int sv = 0, ev = 0;
        if (lane < nrows) {
            sv = ST[(ylo + lane) * GRID + xlo];
            ev = ST[(ylo + lane) * GRID + xhi + 1];
        }

        // ---- pass 1: per-lane min of d^2 over candidates ----
        float mn = INF;
        for (int r = 0; r < nrows; ++r) {
            const int s = __shfl(sv, r), e = __shfl(ev, r);
            for (int j = s + lane; j < e; j += 64) {
                const float2 p = PS[j];
                const float dx = q.x - p.x, dy = q.y - p.y;
                const float d2 = __builtin_fmaf(dy, dy, __fmul_rn(dx, dx));
                mn = fminf(mn, d2);
            }
        }

        // ---- tau^2 = 32nd smallest of the 64 lane minima (bitonic-64) ----
        // <=31 candidates are strictly < d2_(32)  =>  32nd lane-min >= d2_(32).
        {
            float v = mn;
#pragma unroll
            for (int k = 2; k <= 64; k <<= 1) {
#pragma unroll
                for (int j = k >> 1; j > 0; j >>= 1) {
                    const float o = __shfl_xor(v, j);
                    const bool up = ((lane & k) == 0), lower = ((lane & j) == 0);
                    const float mnv = fminf(v, o), mxv = fmaxf(v, o);
                    v = (lower == up) ? mnv : mxv;
                }
            }
            mn = __shfl(v, 31);
        }
        const float tau2b = mn * (1.0f + 4e-6f);

        // ---- pass 2: compact survivors (exact numpy-semantics distance) ----
        int base = 0;
        for (int r = 0; r < nrows; ++r) {
            const int s = __shfl(sv, r), e = __shfl(ev, r);
            for (int j0 = s; j0 < e; j0 += 64) {
                const int j = j0 + lane;
                const bool valid = (j < e);
                float2 p = make_float2(0.f, 0.f);
                if (valid) p = PS[j];
                const float dx = q.x - p.x, dy = q.y - p.y;
                const float d2 = __builtin_fmaf(dy, dy, __fmul_rn(dx, dx));
                const bool pred = valid && (d2 <= tau2b);
                const unsigned long long bm = __ballot(pred);
                if (bm) {
                    const float ex = __fsqrt_rn(__fadd_rn(__fmul_rn(dx, dx),
                                                          __fmul_rn(dy, dy)));
                    const int pos = base + __popcll(bm & lmlt);
                    if (pred && pos < CAP)
                        KEY[wslot][pos] =
                            ((unsigned long long)__float_as_uint(ex) << 32) | (unsigned)IS[j];
                    base += __popcll(bm);
                }
            }
        }

        if (base <= CAP) {
            if (lane >= base)      KEY[wslot][lane]      = ~0ull;
            if (lane + 64 >= base) KEY[wslot][lane + 64] = ~0ull;
            unsigned long long k0 = KEY[wslot][lane];
            unsigned long long k1 = KEY[wslot][lane + 64];
            // bitonic sort 128 u64 keys ascending (u64 order == lex (d, idx))
#pragma unroll
            for (int k = 2; k <= 128; k <<= 1) {
#pragma unroll
                for (int j = k >> 1; j > 0; j >>= 1) {
                    if (j == 64) {
                        const unsigned long long lo = (k0 < k1) ? k0 : k1;
                        const unsigned long long hi = (k0 < k1) ? k1 : k0;
                        k0 = lo; k1 = hi;
                    } else {
                        const unsigned long long o0 = __shfl_xor(k0, j);
                        const unsigned long long o1 = __shfl_xor(k1, j);
                        const bool lower = ((lane & j) == 0);
                        const bool up0 = ((lane & k) == 0);
                        const bool up1 = (((lane + 64) & k) == 0);
                        k0 = ((lower == up0) == (k0 < o0)) ? k0 : o0;
                        k1 = ((lower == up1) == (k1 < o1)) ? k1 : o1;
                    }
                }
            }
            bd = __uint_as_float((unsigned)(k0 >> 32));
            bi = (int)(unsigned)(k0 & 0xffffffffull);
        } else {
            // overflow fallback (astronomically rare): serial insertion, exact
            float fd = INF; int fi = 0x7FFFFFFF;
            for (int r = 0; r < nrows; ++r) {
                const int s = __shfl(sv, r), e = __shfl(ev, r);
                for (int j0 = s; j0 < e; j0 += 64) {
                    const int j = j0 + lane;
                    const bool valid = (j < e);
                    float2 p = make_float2(0.f, 0.f);
                    int vi0 = 0x7FFFFFFF;
                    if (valid) { p = PS[j]; vi0 = IS[j]; }
                    const float dx = q.x - p.x, dy = q.y - p.y;
                    const float d2 = __builtin_fmaf(dy, dy, __fmul_rn(dx, dx));
                    unsigned long long cm = __ballot(valid && (d2 <= tau2b));
                    const float ex = __fsqrt_rn(__fadd_rn(__fmul_rn(dx, dx),
                                                          __fmul_rn(dy, dy)));
                    while (cm) {
                        const int l = __builtin_ctzll(cm); cm &= cm - 1;
                        const float v  = __shfl(ex, l);
                        const int   vi = __shfl(vi0, l);
                        const bool cl = (fd < v) || (fd == v && fi < vi);
                        const int pos = (int)__popcll(__ballot(cl));
                        const float sd = __shfl_up(fd, 1);
                        const int   si = __shfl_up(fi, 1);
                        fd = (lane < pos) ? fd : ((lane == pos) ? v  : sd);
                        fi = (lane < pos) ? fi : ((lane == pos) ? vi : si);
                    }
                }
            }
            bd = fd; bi = fi;
        }

        // ---- exactness check: 32nd distance must beat the unexamined region ----
        const float tau = __shfl(bd, 31);          // NaN if < 32 candidates
        float g = INF;
        if (xlo > 0)        g = fminf(g, q.x - (float)xlo * h);
        if (xhi < GRID - 1) g = fminf(g, (float)(xhi + 1) * h - q.x);
        if (ylo > 0)        g = fminf(g, q.y - (float)ylo * h);
        if (yhi < GRID - 1) g = fminf(g, (float)(yhi + 1) * h - q.y);
        if (tau < g * (1.0f - 4e-6f)) break;       // NaN -> expand
        L += 2;
        if (L > GRID - 1) L = GRID - 1;            // full box => g = INF => terminate
    }

    // ---- outputs 0 and 1: uiv_k and idx (as float) ----
    if (lane < KK) {
        const float2 pk = P[bi];
        float2 u;
        u.x = q.x - pk.x;
        u.y = q.y - pk.y;
        ((float2*)out_uiv)[(size_t)wid * KK + lane] = u;
        out_idx[(size_t)wid * KK + lane] = (float)bi;
    }

    // ---- T[e][i] = sum_k exp(-256*(r_k - mu_e)^2) * values_in[b, idx_k, i] ----
    {
        const int e  = lane >> 2;
        const int ib = (lane & 3) << 3;
        const float mu = (float)e * (1.0f / 15.0f);
        float acc0 = 0.f, acc1 = 0.f, acc2 = 0.f, acc3 = 0.f;
        float acc4 = 0.f, acc5 = 0.f, acc6 = 0.f, acc7 = 0.f;
#pragma unroll
        for (int k = 0; k < KK; ++k) {
            const float rk  = __shfl(bd, k);
            const int   bik = __shfl(bi, k);
            const float dl  = rk - mu;
            const float w   = __expf(-256.0f * dl * dl);
            const float4* vr = (const float4*)(values_in + ((size_t)b * NN + bik) * CIN + ib);
            const float4 v0 = vr[0];
            const float4 v1 = vr[1];
            acc0 += w * v0.x; acc1 += w * v0.y; acc2 += w * v0.z; acc3 += w * v0.w;
            acc4 += w * v1.x; acc5 += w * v1.y; acc6 += w * v1.z; acc7 += w * v1.w;
        }
        float* tw = &TL[wslot][e][ib];
        tw[0] = acc0; tw[1] = acc1; tw[2] = acc2; tw[3] = acc3;
        tw[4] = acc4; tw[5] = acc5; tw[6] = acc6; tw[7] = acc7;
    }

    __syncthreads();

    // ---- out[o] = (1/K) * sum_{e,i} coeffT[e][o][i] * T[e][i] + bias[o] ----
    {
        const int o = lane & 31;
        const int hh = lane >> 5;
        float s = 0.f;
        const float* TW = &TL[wslot][0][0];
        for (int e = hh * 8; e < hh * 8 + 8; ++e) {
            const float4* crow = (const float4*)(coeffT + ((size_t)e * COUT + o) * CIN);
            const float4* trow = (const float4*)(TW + e * 36);
#pragma unroll
            for (int i4 = 0; i4 < 8; ++i4) {
                const float4 c  = crow[i4];
                const float4 tv = trow[i4];
                s += c.x * tv.x + c.y * tv.y + c.z * tv.z + c.w * tv.w;
            }
        }
        s += __shfl_xor(s, 32);
        if (lane < 32) {
            out_val[(size_t)wid * COUT + o] = s * (1.0f / 32.0f) + bias[o];
        }
    }
}

extern "C" void kernel_launch(void* const* d_in, const int* in_sizes, int n_in,
                              void* d_out, int out_size, void* d_ws, size_t ws_size,
                              hipStream_t stream) {
    const float* points_in  = (const float*)d_in[0];
    const float* values_in  = (const float*)d_in[1];
    const float* points_out = (const float*)d_in[2];
    const float* coeff      = (const float*)d_in[3];
    const float* bias       = (const float*)d_in[4];

    float* out     = (float*)d_out;
    float* out_uiv = out;                                        // B*M*K*2
    float* out_idx = out + (size_t)BB * MM * KK * 2;             // B*M*K
    float* out_val = out_idx + (size_t)BB * MM * KK;             // B*M*COUT

    char* ws = (char*)d_ws;
    float*  coeffT = (float*)(ws + OFS_COEFFT);
    int*    counts = (int*)  (ws + OFS_COUNTS);
    int*    cursor = (int*)  (ws + OFS_CURSOR);
    int*    strts  = (int*)  (ws + OFS_STARTS);
    float2* pts_s  = (float2*)(ws + OFS_PTSS);
    int*    idx_s  = (int*)  (ws + OFS_IDXS);

    hipLaunchKernelGGL(transpose_coeff, dim3(64), dim3(256), 0, stream, coeff, coeffT);
    hipLaunchKernelGGL(bin_zero, dim3(16), dim3(256), 0, stream, counts);
    hipLaunchKernelGGL(bin_count, dim3(64), dim3(256), 0, stream, points_in, counts);
    hipLaunchKernelGGL(bin_scan, dim3(1), dim3(1024), 0, stream, counts, strts);
    hipLaunchKernelGGL(bin_scatter, dim3(64), dim3(256), 0, stream,
                       points_in, strts, cursor, pts_s, idx_s);

    const int blocks = (BB * MM) / WPB;                          // 4096
    hipLaunchKernelGGL(conv_query, dim3(blocks), dim3(256), 0, stream,
                       pts_s, idx_s, strts, points_in, values_in, points_out,
                       coeffT, bias, out_uiv, out_idx, out_val);
}

// Round 5
// 177.833 us; speedup vs baseline: 1.8363x; 1.0367x over previous
//
#include <hip/hip_runtime.h>
#include <cstdint>
#include <cstddef>

// Problem constants (from reference)
constexpr int BB   = 2;
constexpr int NN   = 8192;
constexpr int MM   = 8192;
constexpr int CIN  = 32;
constexpr int COUT = 32;
constexpr int EE   = 16;
constexpr int KK   = 32;
constexpr int GRID = 32;              // binning grid (h = 1/32, ~8 pts/cell)
constexpr int NCELL = GRID * GRID;

#define QPB 8          // queries per block (256 threads, 32 lanes/query)
#define CAP 128

// Workspace layout (bytes)
constexpr size_t OFS_COEFFT = 0;        // 16384 f = 65536 B
constexpr size_t OFS_COUNTS = 65536;    // 2*1024 i = 8192 B
constexpr size_t OFS_CURSOR = 73728;    // 2*1024 i = 8192 B
constexpr size_t OFS_STARTS = 81920;    // 2*1025 i = 8200 B (pad to 8704)
constexpr size_t OFS_PTSS   = 90624;    // 2*8192 float2 = 131072 B
constexpr size_t OFS_IDXS   = 221696;   // 2*8192 i = 65536 B  (total 287232 B)

// ---- coeff [CIN][COUT][E] -> coeffT [E][COUT][CIN] ------------------------------
__global__ __launch_bounds__(256) void transpose_coeff(const float* __restrict__ coeff,
                                                       float* __restrict__ coeffT) {
    int tid = blockIdx.x * 256 + threadIdx.x;
    if (tid >= EE * COUT * CIN) return;
    int i = tid & 31;
    int o = (tid >> 5) & 31;
    int e = tid >> 10;
    coeffT[tid] = coeff[(i * COUT + o) * EE + e];
}

// ---- binning: zero, count, scan, scatter ----------------------------------------
__global__ __launch_bounds__(256) void bin_zero(int* __restrict__ p) {
    int t = blockIdx.x * 256 + threadIdx.x;
    if (t < 2 * 2 * NCELL) p[t] = 0;
}

__device__ __forceinline__ int cell_of(float2 p) {
    int cx = min(GRID - 1, max(0, (int)(p.x * (float)GRID)));
    int cy = min(GRID - 1, max(0, (int)(p.y * (float)GRID)));
    return cy * GRID + cx;
}

__global__ __launch_bounds__(256) void bin_count(const float* __restrict__ pts,
                                                 int* __restrict__ counts) {
    int t = blockIdx.x * 256 + threadIdx.x;
    int b = t >> 13, i = t & (NN - 1);
    float2 p = ((const float2*)pts)[(size_t)b * NN + i];
    atomicAdd(&counts[b * NCELL + cell_of(p)], 1);
}

__global__ __launch_bounds__(1024) void bin_scan(const int* __restrict__ counts,
                                                 int* __restrict__ starts) {
    __shared__ int sm[NCELL];
    const int t = threadIdx.x;
    for (int b = 0; b < BB; ++b) {
        sm[t] = counts[b * NCELL + t];
        __syncthreads();
        for (int off = 1; off < NCELL; off <<= 1) {
            int v = (t >= off) ? sm[t - off] : 0;
            __syncthreads();
            sm[t] += v;
            __syncthreads();
        }
        starts[b * (NCELL + 1) + t + 1] = sm[t];
        if (t == 0) starts[b * (NCELL + 1)] = 0;
        __syncthreads();
    }
}

__global__ __launch_bounds__(256) void bin_scatter(const float* __restrict__ pts,
                                                   const int* __restrict__ starts,
                                                   int* __restrict__ cursor,
                                                   float2* __restrict__ pts_s,
                                                   int* __restrict__ idx_s) {
    int t = blockIdx.x * 256 + threadIdx.x;
    int b = t >> 13, i = t & (NN - 1);
    float2 p = ((const float2*)pts)[(size_t)b * NN + i];
    int cell = cell_of(p);
    int pos = starts[b * (NCELL + 1) + cell] + atomicAdd(&cursor[b * NCELL + cell], 1);
    pts_s[(size_t)b * NN + pos] = p;     // intra-cell order nondeterministic; final
    idx_s[(size_t)b * NN + pos] = i;     // sort by (d, orig idx) makes output exact.
}

// ---- main query kernel: one HALF-WAVE (32 lanes) per output point ---------------
__global__ __launch_bounds__(256) void conv_query(
    const float2* __restrict__ pts_s, const int* __restrict__ idx_s,
    const int* __restrict__ starts,
    const float* __restrict__ points_in, const float* __restrict__ values_in,
    const float* __restrict__ points_out,
    const float* __restrict__ coeffT, const float* __restrict__ bias,
    float* __restrict__ out_uiv, float* __restrict__ out_idx,
    float* __restrict__ out_val)
{
    __shared__ alignas(16) float TL[QPB][EE][36];
    __shared__ unsigned long long KEY[QPB][CAP];

    const int tid   = threadIdx.x;
    const int sl    = tid & 31;            // sub-lane within the query's half-wave
    const int qslot = tid >> 5;            // 0..7
    const int half  = qslot & 1;           // which half of the wave
    const int wid   = blockIdx.x * QPB + qslot;
    const int b     = wid >> 13;
    const int m     = wid & (MM - 1);

    const float2* PS = pts_s + (size_t)b * NN;
    const int*    IS = idx_s + (size_t)b * NN;
    const int*    ST = starts + b * (NCELL + 1);
    const float2* P  = ((const float2*)points_in) + (size_t)b * NN;
    const float2  q  = ((const float2*)points_out)[(size_t)b * MM + m];

    const float INF = __builtin_inff();
    const float h = 1.0f / (float)GRID;
    const int cx = min(GRID - 1, max(0, (int)(q.x * (float)GRID)));
    const int cy = min(GRID - 1, max(0, (int)(q.y * (float)GRID)));
    const unsigned lmlt32 = (1u << sl) - 1u;

    float bd;   // sorted exact distance (sub-lane sl holds entry #sl)
    int   bi;   // sorted original index
    int L = 2;

    for (;;) {
        const int xlo = max(cx - L, 0), xhi = min(cx + L, GRID - 1);
        const int ylo = max(cy - L, 0), yhi = min(cy + L, GRID - 1);
        const int nrows = yhi - ylo + 1;          // <= 32

        int sv = 0, ev = 0;
        if (sl < nrows) {
            sv = ST[(ylo + sl) * GRID + xlo];
            ev = ST[(ylo + sl) * GRID + xhi + 1];
        }

        // ---- pass 1: per-lane min1/min2 of d^2 over candidates ----
        float mn1 = INF, mn2 = INF;
        for (int r = 0; r < nrows; ++r) {
            const int s = __shfl(sv, r, 32), e = __shfl(ev, r, 32);
            for (int j = s + sl; j < e; j += 32) {
                const float2 p = PS[j];
                const float dx = q.x - p.x, dy = q.y - p.y;
                const float d2 = __builtin_fmaf(dy, dy, __fmul_rn(dx, dx));
                const float big = fmaxf(mn1, d2);
                mn1 = fminf(mn1, d2);
                mn2 = fminf(mn2, big);
            }
        }

        // ---- tau^2 = 16th smallest of the 32 lane-min2 (bitonic-32) ----
        // <=31 cands strictly < d2_(32) => <=15 lanes hold >=2 such cands
        // => at most 15 lane-min2 strictly below => 16th smallest >= d2_(32).
        {
            float v = mn2;
#pragma unroll
            for (int k = 2; k <= 32; k <<= 1) {
#pragma unroll
                for (int j = k >> 1; j > 0; j >>= 1) {
                    const float o = __shfl_xor(v, j, 32);
                    const bool up = ((sl & k) == 0), lower = ((sl & j) == 0);
                    const float mnv = fminf(v, o), mxv = fmaxf(v, o);
                    v = (lower == up) ? mnv : mxv;
                }
            }
            mn2 = __shfl(v, 15, 32);
        }
        const float tau2b = mn2 * (1.0f + 4e-6f);

        // ---- pass 2: compact survivors (exact numpy-semantics distance) ----
        int base = 0;
        for (int r = 0; r < nrows; ++r) {
            const int s = __shfl(sv, r, 32), e = __shfl(ev, r, 32);
            for (int j0 = s; j0 < e; j0 += 32) {
                const int j = j0 + sl;
                const bool valid = (j < e);
                float2 p = make_float2(0.f, 0.f);
                if (valid) p = PS[j];
                const float dx = q.x - p.x, dy = q.y - p.y;
                const float d2 = __builtin_fmaf(dy, dy, __fmul_rn(dx, dx));
                const bool pred = valid && (d2 <= tau2b);
                const unsigned bm = (unsigned)(__ballot(pred) >> (half << 5));
                if (bm) {
                    const float ex = __fsqrt_rn(__fadd_rn(__fmul_rn(dx, dx),
                                                          __fmul_rn(dy, dy)));
                    const int pos = base + __popc(bm & lmlt32);
                    if (pred && pos < CAP)
                        KEY[qslot][pos] =
                            ((unsigned long long)__float_as_uint(ex) << 32) | (unsigned)IS[j];
                    base += __popc(bm);
                }
            }
        }

        if (base <= CAP) {
            unsigned long long K0 = (sl      < base) ? KEY[qslot][sl]      : ~0ull;
            unsigned long long K1 = (sl + 32 < base) ? KEY[qslot][sl + 32] : ~0ull;
            unsigned long long K2 = (sl + 64 < base) ? KEY[qslot][sl + 64] : ~0ull;
            unsigned long long K3 = (sl + 96 < base) ? KEY[qslot][sl + 96] : ~0ull;

            // bitonic sort of 128 u64 keys on 32 lanes x 4 regs (v = reg*32 + sl)
            auto SWAPIN = [](unsigned long long& a, unsigned long long& b, bool asc) {
                const unsigned long long lo = (a < b) ? a : b;
                const unsigned long long hi = (a < b) ? b : a;
                a = asc ? lo : hi; b = asc ? hi : lo;
            };
#pragma unroll
            for (int k = 2; k <= 128; k <<= 1) {
                if (k == 64)  { SWAPIN(K0, K1, true); SWAPIN(K2, K3, false); }
                if (k == 128) { SWAPIN(K0, K2, true); SWAPIN(K1, K3, true);
                                SWAPIN(K0, K1, true); SWAPIN(K2, K3, true); }
                const int js = ((k >> 1) > 16) ? 16 : (k >> 1);
#pragma unroll
                for (int j = js; j > 0; j >>= 1) {
                    const bool lower = ((sl & j) == 0);
                    bool a0, a1, a2, a3;
                    if (k <= 16)      { const bool a = ((sl & k) == 0); a0 = a1 = a2 = a3 = a; }
                    else if (k == 32) { a0 = true; a1 = false; a2 = true;  a3 = false; }
                    else if (k == 64) { a0 = true; a1 = true;  a2 = false; a3 = false; }
                    else              { a0 = a1 = a2 = a3 = true; }
                    const unsigned long long o0 = __shfl_xor(K0, j, 32);
                    const unsigned long long o1 = __shfl_xor(K1, j, 32);
                    const unsigned long long o2 = __shfl_xor(K2, j, 32);
                    const unsigned long long o3 = __shfl_xor(K3, j, 32);
                    K0 = ((K0 < o0) == (lower == a0)) ? K0 : o0;
                    K1 = ((K1 < o1) == (lower == a1)) ? K1 : o1;
                    K2 = ((K2 < o2) == (lower == a2)) ? K2 : o2;
                    K3 = ((K3 < o3) == (lower == a3)) ? K3 : o3;
                }
            }
            bd = __uint_as_float((unsigned)(K0 >> 32));
            bi = (int)(unsigned)(K0 & 0xffffffffull);
        } else {
            // overflow fallback (rare, deterministic-correct): serial insertion
            float fd = INF; int fi = 0x7FFFFFFF;
            for (int r = 0; r < nrows; ++r) {
                const int s = __shfl(sv, r, 32), e = __shfl(ev, r, 32);
                for (int j0 = s; j0 < e; j0 += 32) {
                    const int j = j0 + sl;
                    const bool valid = (j < e);
                    float2 p = make_float2(0.f, 0.f);
                    int vi0 = 0x7FFFFFFF;
                    if (valid) { p = PS[j]; vi0 = IS[j]; }
                    const float dx = q.x - p.x, dy = q.y - p.y;
                    const float d2 = __builtin_fmaf(dy, dy, __fmul_rn(dx, dx));
                    unsigned cm = (unsigned)(__ballot(valid && (d2 <= tau2b)) >> (half << 5));
                    const float ex = __fsqrt_rn(__fadd_rn(__fmul_rn(dx, dx),
                                                          __fmul_rn(dy, dy)));
                    while (cm) {
                        const int l = __builtin_ctz(cm); cm &= cm - 1;
                        const float v  = __shfl(ex, l, 32);
                        const int   vi = __shfl(vi0, l, 32);
                        const bool cl = (fd < v) || (fd == v && fi < vi);
                        const int pos = __popc((unsigned)(__ballot(cl) >> (half << 5)));
                        const float sd = __shfl_up(fd, 1, 32);
                        const int   si = __shfl_up(fi, 1, 32);
                        fd = (sl < pos) ? fd : ((sl == pos) ? v  : sd);
                        fi = (sl < pos) ? fi : ((sl == pos) ? vi : si);
                    }
                }
            }
            bd = fd; bi = fi;
        }

        // ---- exactness check: 32nd distance must beat the unexamined region ----
        const float tau = __shfl(bd, 31, 32);      // NaN if < 32 candidates
        float g = INF;
        if (xlo > 0)        g = fminf(g, q.x - (float)xlo * h);
        if (xhi < GRID - 1) g = fminf(g, (float)(xhi + 1) * h - q.x);
        if (ylo > 0)        g = fminf(g, q.y - (float)ylo * h);
        if (yhi < GRID - 1) g = fminf(g, (float)(yhi + 1) * h - q.y);
        if (tau < g * (1.0f - 4e-6f)) break;       // NaN -> expand
        L += 2;
        if (L > GRID - 1) L = GRID - 1;            // full box => g = INF => terminate
    }

    // ---- outputs 0 and 1: uiv_k and idx (as float) ----
    {
        const float2 pk = P[bi];
        float2 u;
        u.x = q.x - pk.x;
        u.y = q.y - pk.y;
        ((float2*)out_uiv)[(size_t)wid * KK + sl] = u;
        out_idx[(size_t)wid * KK + sl] = (float)bi;
    }

    // ---- T[e][i] = sum_k exp(-256*(r_k - mu_e)^2) * values_in[b, idx_k, i] ----
    {
        const int e  = sl >> 1;                 // 0..15
        const int ib = (sl & 1) << 4;           // 0 or 16
        const float mu = (float)e * (1.0f / 15.0f);
        float4 A0 = make_float4(0.f, 0.f, 0.f, 0.f);
        float4 A1 = A0, A2 = A0, A3 = A0;
#pragma unroll
        for (int k = 0; k < KK; ++k) {
            const float rk  = __shfl(bd, k, 32);
            const int   bik = __shfl(bi, k, 32);
            const float dl  = rk - mu;
            const float w   = __expf(-256.0f * dl * dl);
            const float4* vr = (const float4*)(values_in + ((size_t)b * NN + bik) * CIN + ib);
            const float4 v0 = vr[0], v1 = vr[1], v2 = vr[2], v3 = vr[3];
            A0.x += w * v0.x; A0.y += w * v0.y; A0.z += w * v0.z; A0.w += w * v0.w;
            A1.x += w * v1.x; A1.y += w * v1.y; A1.z += w * v1.z; A1.w += w * v1.w;
            A2.x += w * v2.x; A2.y += w * v2.y; A2.z += w * v2.z; A2.w += w * v2.w;
            A3.x += w * v3.x; A3.y += w * v3.y; A3.z += w * v3.z; A3.w += w * v3.w;
        }
        float4* tw = (float4*)&TL[qslot][e][ib];
        tw[0] = A0; tw[1] = A1; tw[2] = A2; tw[3] = A3;
    }

    __syncthreads();

    // ---- out[o] = (1/K) * sum_{e,i} coeffT[e][o][i] * T[e][i] + bias[o] ----
    {
        const int o = sl;
        float s = 0.f;
        const float* TW = &TL[qslot][0][0];
#pragma unroll
        for (int e2 = 0; e2 < EE; ++e2) {
            const float4* crow = (const float4*)(coeffT + ((size_t)e2 * COUT + o) * CIN);
            const float4* trow = (const float4*)(TW + e2 * 36);
#pragma unroll
            for (int i4 = 0; i4 < 8; ++i4) {
                const float4 c  = crow[i4];
                const float4 tv = trow[i4];
                s += c.x * tv.x + c.y * tv.y + c.z * tv.z + c.w * tv.w;
            }
        }
        out_val[(size_t)wid * COUT + o] = s * (1.0f / 32.0f) + bias[o];
    }
}

extern "C" void kernel_launch(void* const* d_in, const int* in_sizes, int n_in,
                              void* d_out, int out_size, void* d_ws, size_t ws_size,
                              hipStream_t stream) {
    const float* points_in  = (const float*)d_in[0];
    const float* values_in  = (const float*)d_in[1];
    const float* points_out = (const float*)d_in[2];
    const float* coeff      = (const float*)d_in[3];
    const float* bias       = (const float*)d_in[4];

    float* out     = (float*)d_out;
    float* out_uiv = out;                                        // B*M*K*2
    float* out_idx = out + (size_t)BB * MM * KK * 2;             // B*M*K
    float* out_val = out_idx + (size_t)BB * MM * KK;             // B*M*COUT

    char* ws = (char*)d_ws;
    float*  coeffT = (float*)(ws + OFS_COEFFT);
    int*    counts = (int*)  (ws + OFS_COUNTS);
    int*    cursor = (int*)  (ws + OFS_CURSOR);
    int*    strts  = (int*)  (ws + OFS_STARTS);
    float2* pts_s  = (float2*)(ws + OFS_PTSS);
    int*    idx_s  = (int*)  (ws + OFS_IDXS);

    hipLaunchKernelGGL(transpose_coeff, dim3(64), dim3(256), 0, stream, coeff, coeffT);
    hipLaunchKernelGGL(bin_zero, dim3(16), dim3(256), 0, stream, counts);
    hipLaunchKernelGGL(bin_count, dim3(64), dim3(256), 0, stream, points_in, counts);
    hipLaunchKernelGGL(bin_scan, dim3(1), dim3(1024), 0, stream, counts, strts);
    hipLaunchKernelGGL(bin_scatter, dim3(64), dim3(256), 0, stream,
                       points_in, strts, cursor, pts_s, idx_s);

    const int blocks = (BB * MM) / QPB;                          // 2048
    hipLaunchKernelGGL(conv_query, dim3(blocks), dim3(256), 0, stream,
                       pts_s, idx_s, strts, points_in, values_in, points_out,
                       coeffT, bias, out_uiv, out_idx, out_val);
}